// Round 4
// baseline (234.785 us; speedup 1.0000x reference)
//
#include <hip/hip_runtime.h>
#include <math.h>

#define EPS 1e-7f
#define FN_PENALTY 10.0f
#define BLOCK 256
#define RPT 4   // rows per thread

__device__ __forceinline__ float waveReduceSum(float v) {
    #pragma unroll
    for (int off = 32; off > 0; off >>= 1)
        v += __shfl_down(v, off, 64);
    return v;
}

__device__ __forceinline__ float4 validate_fix(float4 b) {
    bool invalid = (b.x > b.z) || (b.y > b.w);
    if (invalid) {
        b.x = fmaxf(b.x, 0.0f);
        b.y = fmaxf(b.y, 0.0f);
        b.z = fmaxf(b.z, 0.0f);
        b.w = fmaxf(b.w, 0.0f);
    }
    b.z = fmaxf(b.z, b.x + 1e-6f);
    b.w = fmaxf(b.w, b.y + 1e-6f);
    return b;
}

__device__ __forceinline__ void accum_row(
    float4 lg, int lbl, float4 pb, float4 tb, float cl, float ct,
    float& s_class, float& s_bbox, float& s_giou, float& s_cut)
{
    // ---- focal class loss ----
    float l0 = lg.x, l1 = lg.y, l2 = lg.z, l3 = lg.w;
    float m = fmaxf(fmaxf(l0, l1), fmaxf(l2, l3));
    float e0 = __expf(l0 - m), e1 = __expf(l1 - m),
          e2 = __expf(l2 - m), e3 = __expf(l3 - m);
    float se = e0 + e1 + e2 + e3;
    lbl &= 3;
    float esel = (lbl == 0) ? e0 : (lbl == 1) ? e1 : (lbl == 2) ? e2 : e3;
    float pt = esel / se;          // exp(lsel - lse), reuses the 4 exps
    float ce = -__logf(pt);        // lse - lsel
    float om = 1.0f - pt;
    s_class += om * om * ce;       // ALPHA=1, GAMMA=2

    // ---- bbox L1 ----
    s_bbox += fabsf(pb.x - tb.x) + fabsf(pb.y - tb.y)
            + fabsf(pb.z - tb.z) + fabsf(pb.w - tb.w);

    // ---- GIoU ----
    float4 b1 = validate_fix(pb);
    float4 b2 = validate_fix(tb);
    float area1 = (b1.z - b1.x) * (b1.w - b1.y);
    float area2 = (b2.z - b2.x) * (b2.w - b2.y);
    float ltx = fmaxf(b1.x, b2.x), lty = fmaxf(b1.y, b2.y);
    float rbx = fminf(b1.z, b2.z), rby = fminf(b1.w, b2.w);
    float iw = fmaxf(rbx - ltx, 0.0f), ih = fmaxf(rby - lty, 0.0f);
    float inter = iw * ih;
    float uni = area1 + area2 - inter;
    float iou = inter / (uni + EPS);
    float ex1 = fminf(b1.x, b2.x), ey1 = fminf(b1.y, b2.y);
    float ex2 = fmaxf(b1.z, b2.z), ey2 = fmaxf(b1.w, b2.w);
    float ew = fmaxf(ex2 - ex1, 0.0f), eh = fmaxf(ey2 - ey1, 0.0f);
    float enc = ew * eh;
    float giou = iou - (enc - uni) / (enc + EPS);
    s_giou += fmaxf(1.0f - giou, 0.0f);

    // ---- weighted BCE ----
    float bce = fmaxf(cl, 0.0f) - cl * ct + __logf(1.0f + __expf(-fabsf(cl)));
    float w = ((ct == 1.0f) && (cl < 0.0f)) ? FN_PENALTY : 1.0f;  // sigmoid<0.5 <=> logit<0
    s_cut += bce * w;
}

__device__ __forceinline__ void block_reduce_store(
    float s_class, float s_bbox, float s_giou, float s_cut,
    float4* __restrict__ out_slot)
{
    s_class = waveReduceSum(s_class);
    s_bbox  = waveReduceSum(s_bbox);
    s_giou  = waveReduceSum(s_giou);
    s_cut   = waveReduceSum(s_cut);

    __shared__ float red[4][4];
    const int lane = threadIdx.x & 63;
    const int wave = threadIdx.x >> 6;
    if (lane == 0) {
        red[wave][0] = s_class;
        red[wave][1] = s_bbox;
        red[wave][2] = s_giou;
        red[wave][3] = s_cut;
    }
    __syncthreads();
    if (threadIdx.x == 0) {
        float4 r;
        r.x = red[0][0] + red[1][0] + red[2][0] + red[3][0];
        r.y = red[0][1] + red[1][1] + red[2][1] + red[3][1];
        r.z = red[0][2] + red[1][2] + red[2][2] + red[3][2];
        r.w = red[0][3] + red[1][3] + red[2][3] + red[3][3];
        *out_slot = r;
    }
}

// Stage 1: 4 rows per thread, packed loads (15 vmem instrs / 4 rows).
__global__ __launch_bounds__(BLOCK) void loss_reduce(
    const float4* __restrict__ pred_logits,
    const int*    __restrict__ labels,
    const float4* __restrict__ pred_boxes,
    const float4* __restrict__ target_boxes,
    const float*  __restrict__ cut_logits,
    const float*  __restrict__ cut_targets,
    float4* __restrict__ block_out, int n)
{
    const int t    = blockIdx.x * BLOCK + threadIdx.x;
    const int base = t * RPT;
    float s_class = 0.0f, s_bbox = 0.0f, s_giou = 0.0f, s_cut = 0.0f;

    if (base + RPT - 1 < n) {
        // packed scalar-stream loads first (needed by every row's compute)
        int4   lbl4 = ((const int4*)labels)[t];
        float4 cl4  = ((const float4*)cut_logits)[t];
        float4 ct4  = ((const float4*)cut_targets)[t];
        // per-row float4 streams: 64 B contiguous per thread per array
        float4 lg0 = pred_logits[base+0], lg1 = pred_logits[base+1],
               lg2 = pred_logits[base+2], lg3 = pred_logits[base+3];
        float4 pb0 = pred_boxes[base+0],  pb1 = pred_boxes[base+1],
               pb2 = pred_boxes[base+2],  pb3 = pred_boxes[base+3];
        float4 tb0 = target_boxes[base+0], tb1 = target_boxes[base+1],
               tb2 = target_boxes[base+2], tb3 = target_boxes[base+3];

        accum_row(lg0, lbl4.x, pb0, tb0, cl4.x, ct4.x, s_class, s_bbox, s_giou, s_cut);
        accum_row(lg1, lbl4.y, pb1, tb1, cl4.y, ct4.y, s_class, s_bbox, s_giou, s_cut);
        accum_row(lg2, lbl4.z, pb2, tb2, cl4.z, ct4.z, s_class, s_bbox, s_giou, s_cut);
        accum_row(lg3, lbl4.w, pb3, tb3, cl4.w, ct4.w, s_class, s_bbox, s_giou, s_cut);
    } else {
        for (int i = base; i < n; ++i)
            accum_row(pred_logits[i], labels[i], pred_boxes[i], target_boxes[i],
                      cut_logits[i], cut_targets[i],
                      s_class, s_bbox, s_giou, s_cut);
    }
    block_reduce_store(s_class, s_bbox, s_giou, s_cut, &block_out[blockIdx.x]);
}

// Stage 2: reduce stage-1 partials -> gridDim partials.
__global__ __launch_bounds__(BLOCK) void reduce_partials(
    const float4* __restrict__ in, int n, float4* __restrict__ out)
{
    float c = 0.0f, b = 0.0f, g = 0.0f, u = 0.0f;
    for (int i = blockIdx.x * BLOCK + threadIdx.x; i < n; i += gridDim.x * BLOCK) {
        float4 r = in[i];
        c += r.x; b += r.y; g += r.z; u += r.w;
    }
    block_reduce_store(c, b, g, u, &out[blockIdx.x]);
}

// Stage 3: one wave reduces stage-2 partials, writes the 5 outputs.
__global__ void finalize_kernel(const float4* __restrict__ in, int n,
                                float* __restrict__ out, float inv_n)
{
    const int lane = threadIdx.x & 63;
    float c = 0.0f, b = 0.0f, g = 0.0f, u = 0.0f;
    for (int i = lane; i < n; i += 64) {
        float4 r = in[i];
        c += r.x; b += r.y; g += r.z; u += r.w;
    }
    c = waveReduceSum(c);
    b = waveReduceSum(b);
    g = waveReduceSum(g);
    u = waveReduceSum(u);
    if (lane == 0) {
        float lc   = fmaxf(c * inv_n, 0.0f);
        float lb   = fmaxf(b * inv_n * 0.25f, 0.0f);  // mean over 4N elems
        float lg   = fmaxf(g * inv_n, 0.0f);
        float lcut = fmaxf(u * inv_n, 0.0f);
        float total = 1.0f * lc + 5.0f * lb + 2.0f * lg + 3.0f * lcut;
        out[0] = total;
        out[1] = lc;
        out[2] = lb;
        out[3] = lg;
        out[4] = lcut;
    }
}

extern "C" void kernel_launch(void* const* d_in, const int* in_sizes, int n_in,
                              void* d_out, int out_size, void* d_ws, size_t ws_size,
                              hipStream_t stream) {
    const float4* pred_logits  = (const float4*)d_in[0];
    const int*    labels       = (const int*)d_in[1];
    const float4* pred_boxes   = (const float4*)d_in[2];
    const float4* target_boxes = (const float4*)d_in[3];
    const float*  cut_logits   = (const float*)d_in[4];
    const float*  cut_targets  = (const float*)d_in[5];
    float4* ws4 = (float4*)d_ws;
    float*  out = (float*)d_out;
    const int n = in_sizes[1];  // rows

    const int grid1 = (n + BLOCK * RPT - 1) / (BLOCK * RPT);  // 4096 @ N=4.19M
    const int grid2 = 64;
    float4* part1 = ws4;                 // grid1 entries
    float4* part2 = ws4 + grid1;         // grid2 entries

    loss_reduce<<<grid1, BLOCK, 0, stream>>>(pred_logits, labels, pred_boxes,
                                             target_boxes, cut_logits, cut_targets,
                                             part1, n);
    reduce_partials<<<grid2, BLOCK, 0, stream>>>(part1, grid1, part2);
    finalize_kernel<<<1, 64, 0, stream>>>(part2, grid2, out, 1.0f / (float)n);
}